// Round 1
// 281.477 us; speedup vs baseline: 1.0458x; 1.0458x over previous
//
#include <hip/hip_runtime.h>
#include <hip/hip_bf16.h>

typedef __bf16 bf16_t;
typedef __bf16 bf16x2 __attribute__((ext_vector_type(2)));
typedef __bf16 bf16x8 __attribute__((ext_vector_type(8)));
typedef float f32x4 __attribute__((ext_vector_type(4)));
typedef float f32x16 __attribute__((ext_vector_type(16)));
typedef int intx4 __attribute__((ext_vector_type(4)));
typedef unsigned int u32;
typedef unsigned long long u64;

#define S_LEN 2048
#define DM 1024
#define NH 16
#define DK 64
#define M_ROWS 4096
#define SCALE_LOG2E 0.1803368801111204f /* 0.125 * log2(e) */

// 64-col bf16 LDS tile: 8 chunks of 8 elems (16B); phys chunk = chunk ^ (row&7).
__device__ __forceinline__ int sw_off(int row, int col) {
  return row * 64 + ((((col >> 3) ^ row) & 7) << 3) + (col & 7);
}

__device__ __forceinline__ bf16x8 cvt8(const float4& a, const float4& b) {
  bf16x8 v;
  v[0] = (__bf16)a.x; v[1] = (__bf16)a.y; v[2] = (__bf16)a.z; v[3] = (__bf16)a.w;
  v[4] = (__bf16)b.x; v[5] = (__bf16)b.y; v[6] = (__bf16)b.z; v[7] = (__bf16)b.w;
  return v;
}

__device__ __forceinline__ void glds16(const bf16_t* g, bf16_t* l) {
  __builtin_amdgcn_global_load_lds(
      (const __attribute__((address_space(1))) void*)g,
      (__attribute__((address_space(3))) void*)l, 16, 0, 0);
}

// pack two f32 -> u32 of 2 bf16 (lo = first)
__device__ __forceinline__ int pk2(float lo, float hi) {
  bf16x2 t;
  t[0] = (__bf16)lo;
  t[1] = (__bf16)hi;
  return __builtin_bit_cast(int, t);
}

// mask int32 [B,1,S,S] -> row-packed u64: mb[(b*32+kw)*2048 + q], bit i = mask[b][q][kw*64+i]
__global__ __launch_bounds__(256) void pack_mask(
    const int* __restrict__ mask, u64* __restrict__ mb)
{
  const int g = blockIdx.x * 256 + threadIdx.x;  // b(1)|kw(5)|q(11)
  const int q = g & 2047;
  const int kw = (g >> 11) & 31;
  const int b = g >> 16;
  const int* src = &mask[((size_t)(b * S_LEN + q)) * S_LEN + kw * 64];
  u64 bits = 0;
  #pragma unroll
  for (int i = 0; i < 16; ++i) {
    const int4 m4 = *(const int4*)&src[i * 4];
    bits |= (u64)(m4.x != 0) << (4 * i);
    bits |= (u64)(m4.y != 0) << (4 * i + 1);
    bits |= (u64)(m4.z != 0) << (4 * i + 2);
    bits |= (u64)(m4.w != 0) << (4 * i + 3);
  }
  mb[g] = bits;
}

// q,k,v fp32 -> Xb bf16 [3][4096][1024]
__global__ __launch_bounds__(256) void cvt_inputs(
    const float* __restrict__ q, const float* __restrict__ k,
    const float* __restrict__ v, bf16_t* __restrict__ Xb)
{
  const int z = blockIdx.y;
  const float* __restrict__ src = (z == 0) ? q : ((z == 1) ? k : v);
  const size_t idx = ((size_t)blockIdx.x * 256 + threadIdx.x) * 8;
  const float4 a = *(const float4*)&src[idx];
  const float4 b = *(const float4*)&src[idx + 4];
  *(bf16x8*)&Xb[(size_t)z * M_ROWS * DM + idx] = cvt8(a, b);
}

// W fp32 [k][n] -> Wt bf16 [n][k]  (z selects Wq/Wk/Wv/Wo)
__global__ __launch_bounds__(256) void transw_kernel(
    const float* __restrict__ Wq, const float* __restrict__ Wk,
    const float* __restrict__ Wv, const float* __restrict__ Wo,
    bf16_t* __restrict__ Wt)
{
  const int z = blockIdx.z;
  const float* __restrict__ W = (z == 0) ? Wq : ((z == 1) ? Wk : ((z == 2) ? Wv : Wo));
  bf16_t* __restrict__ out = Wt + (size_t)z * DM * DM;
  __shared__ float tile[64][65];
  const int tx = threadIdx.x & 31, ty = threadIdx.x >> 5;
  const int k0 = blockIdx.x * 64, n0 = blockIdx.y * 64;
  #pragma unroll
  for (int j = 0; j < 8; ++j) {
    const float2 v = *(const float2*)&W[(size_t)(k0 + ty + 8 * j) * DM + n0 + tx * 2];
    tile[ty + 8 * j][tx * 2] = v.x;
    tile[ty + 8 * j][tx * 2 + 1] = v.y;
  }
  __syncthreads();
  #pragma unroll
  for (int j = 0; j < 8; ++j) {
    const int a = ty + 8 * j;
    bf16x2 p;
    p[0] = (__bf16)tile[tx * 2][a];
    p[1] = (__bf16)tile[tx * 2 + 1][a];
    *(bf16x2*)&out[(size_t)(n0 + a) * DM + k0 + tx * 2] = p;
  }
}

// m97-style 128x128 BK=32 BT-GEMM: C = A[4096xK] @ Bt^T + bias
__device__ __forceinline__ void gemm128_body(
    const bf16_t* __restrict__ A, const bf16_t* __restrict__ Bt,
    const float* __restrict__ bias, bf16_t* __restrict__ outb,
    float* __restrict__ outf)
{
  __shared__ __align__(16) bf16_t As[128 * 32];
  __shared__ __align__(16) bf16_t Bs[128 * 32];
  const int t = threadIdx.x, w = t >> 6, L = t & 63, quad = L >> 4, l16 = L & 15;
  const int m0 = blockIdx.x * 128, n0 = blockIdx.y * 128;
  const int mb = 64 * (w & 1), nb = 64 * (w >> 1);
  const int rowS = t >> 2, subS = (t & 3) * 8;

  f32x4 acc[4][4] = {};
  for (int k0 = 0; k0 < DM; k0 += 32) {
    __syncthreads();
    glds16(&A[(size_t)(m0 + rowS) * DM + k0 + subS],        &As[t * 8]);
    glds16(&A[(size_t)(m0 + 64 + rowS) * DM + k0 + subS],   &As[2048 + t * 8]);
    glds16(&Bt[(size_t)(n0 + rowS) * DM + k0 + subS],       &Bs[t * 8]);
    glds16(&Bt[(size_t)(n0 + 64 + rowS) * DM + k0 + subS],  &Bs[2048 + t * 8]);
    __syncthreads();
    bf16x8 af[4], bfr[4];
    #pragma unroll
    for (int mt = 0; mt < 4; ++mt)
      af[mt] = *(const bf16x8*)&As[(mb + 16 * mt + l16) * 32 + quad * 8];
    #pragma unroll
    for (int ct = 0; ct < 4; ++ct)
      bfr[ct] = *(const bf16x8*)&Bs[(nb + 16 * ct + l16) * 32 + quad * 8];
    #pragma unroll
    for (int mt = 0; mt < 4; ++mt)
      #pragma unroll
      for (int ct = 0; ct < 4; ++ct)
        acc[mt][ct] = __builtin_amdgcn_mfma_f32_16x16x32_bf16(af[mt], bfr[ct], acc[mt][ct], 0, 0, 0);
  }
  #pragma unroll
  for (int mt = 0; mt < 4; ++mt)
    #pragma unroll
    for (int ct = 0; ct < 4; ++ct)
      #pragma unroll
      for (int r = 0; r < 4; ++r) {
        const int row = m0 + mb + 16 * mt + quad * 4 + r;
        const int n = n0 + nb + 16 * ct + l16;
        const float val = acc[mt][ct][r] + bias[n];
        if (outb) outb[(size_t)row * DM + n] = (__bf16)val;
        else      outf[(size_t)row * DM + n] = val;
      }
}

__global__ __launch_bounds__(256) void gemm_qkv(
    const bf16_t* __restrict__ Xb, const bf16_t* __restrict__ Wt,
    const float* __restrict__ bq, const float* __restrict__ bk,
    const float* __restrict__ bv, bf16_t* __restrict__ QKVb)
{
  const int z = blockIdx.z;
  gemm128_body(Xb + (size_t)z * M_ROWS * DM, Wt + (size_t)z * DM * DM,
               (z == 0) ? bq : ((z == 1) ? bk : bv),
               QKVb + (size_t)z * M_ROWS * DM, nullptr);
}

__global__ __launch_bounds__(256) void gemm_out(
    const bf16_t* __restrict__ ctx, const bf16_t* __restrict__ Wto,
    const float* __restrict__ bo, float* __restrict__ out)
{
  gemm128_body(ctx, Wto, bo, nullptr, out);
}

// Vb [4096][1024] (head cols) -> Vtw [bh][dv=64][key=2048]
__global__ __launch_bounds__(256) void transpV(
    const bf16_t* __restrict__ Vb, bf16_t* __restrict__ Vtw)
{
  __shared__ bf16_t Tr[64 * 72];
  const int t = threadIdx.x;
  const int key0 = blockIdx.x * 64;
  const int bh = blockIdx.y, b = bh >> 4, h = bh & 15;
  const int r = t >> 2, c = (t & 3) * 16;
  const bf16_t* src = &Vb[(size_t)(b * S_LEN + key0 + r) * DM + h * DK + c];
  const bf16x8 v0 = *(const bf16x8*)src;
  const bf16x8 v1 = *(const bf16x8*)(src + 8);
  #pragma unroll
  for (int j = 0; j < 8; ++j) {
    Tr[r * 72 + c + j] = v0[j];
    Tr[r * 72 + c + 8 + j] = v1[j];
  }
  __syncthreads();
  const int dv = t >> 2, kc = (t & 3) * 16;
  bf16_t ov[16];
  #pragma unroll
  for (int j = 0; j < 16; ++j) ov[j] = Tr[(kc + j) * 72 + dv];
  bf16_t* dst = &Vtw[((size_t)bh * DK + dv) * S_LEN + key0 + kc];
  *(bf16x8*)dst = *(bf16x8*)&ov[0];
  *(bf16x8*)(dst + 8) = *(bf16x8*)&ov[8];
}

// Flash attention, swapped-QK^T (T12): S^T = mfma(K,Q) puts P with col=q=lane&31,
// rows=key at crow(r,h5)=(r&3)+8*(r>>2)+4*h5. P->bf16 B-fragments built fully
// in-register via pk2 + permlane32_swap; PV computes O^T = mfma(V^T, Pfrag).
// No Ps LDS round-trip; denominator is one scalar/lane; epilogue transposes via Qs.
__global__ __launch_bounds__(256, 2) void attn_kernel(
    const bf16_t* __restrict__ Qb, const bf16_t* __restrict__ Kb,
    const bf16_t* __restrict__ Vtw, const u64* __restrict__ mb,
    bf16_t* __restrict__ ctx)
{
  __shared__ __align__(16) bf16_t Qs[128 * 64];
  __shared__ __align__(16) bf16_t Ks[64 * 64];
  __shared__ __align__(16) bf16_t Vts[64 * 64];

  const int t = threadIdx.x, w = t >> 6, L = t & 63;
  const int l31 = L & 31, h5 = L >> 5;
  const int q0 = blockIdx.x * 128;
  const int bh = blockIdx.y, b = bh >> 4, h = bh & 15;
  const int sr = t >> 2, sc = (t & 3) * 16;

  // stage Q (128 rows x 64)
  #pragma unroll
  for (int half = 0; half < 2; ++half) {
    const int row = half * 64 + sr;
    const bf16_t* s = &Qb[(size_t)(b * S_LEN + q0 + row) * DM + h * DK + sc];
    *(bf16x8*)&Qs[sw_off(row, sc)]     = *(const bf16x8*)s;
    *(bf16x8*)&Qs[sw_off(row, sc + 8)] = *(const bf16x8*)(s + 8);
  }

  const int qg = q0 + 32 * w + l31;                       // this lane's q row
  const u64* pm = &mb[(size_t)b * 32 * S_LEN + qg];       // advances by S_LEN per kt
  const bf16_t* pk_src = &Kb[(size_t)(b * S_LEN + sr) * DM + h * DK + sc];
  const bf16_t* pv_src = &Vtw[((size_t)bh * DK + sr) * S_LEN + sc];

  // prefetch tile 0
  bf16x8 kp0, kp1, vp0, vp1;
  u64 mp;
  kp0 = *(const bf16x8*)pk_src; kp1 = *(const bf16x8*)(pk_src + 8);
  vp0 = *(const bf16x8*)pv_src; vp1 = *(const bf16x8*)(pv_src + 8);
  mp = *pm;
  pk_src += (size_t)64 * DM; pv_src += 64; pm += S_LEN;

  f32x16 O[2] = {};
  float l_lane = 0.f;

  for (int kt = 0; kt < S_LEN / 64; ++kt) {
    __syncthreads();
    *(bf16x8*)&Ks[sw_off(sr, sc)]      = kp0;
    *(bf16x8*)&Ks[sw_off(sr, sc + 8)]  = kp1;
    *(bf16x8*)&Vts[sw_off(sr, sc)]     = vp0;
    *(bf16x8*)&Vts[sw_off(sr, sc + 8)] = vp1;
    const u64 mcur = mp;
    __syncthreads();

    if (kt + 1 < S_LEN / 64) {
      kp0 = *(const bf16x8*)pk_src; kp1 = *(const bf16x8*)(pk_src + 8);
      vp0 = *(const bf16x8*)pv_src; vp1 = *(const bf16x8*)(pv_src + 8);
      mp = *pm;
      pk_src += (size_t)64 * DM; pv_src += 64; pm += S_LEN;
    }

    // S^T = K Q^T: D[key][q], col = q = l31, rows = key via crow(r,h5)
    f32x16 sacc[2] = {};
    #pragma unroll
    for (int ks = 0; ks < 4; ++ks) {
      const bf16x8 qf = *(const bf16x8*)&Qs[sw_off(32 * w + l31, ks * 16 + 8 * h5)];
      #pragma unroll
      for (int nt = 0; nt < 2; ++nt) {
        const bf16x8 kf = *(const bf16x8*)&Ks[sw_off(nt * 32 + l31, ks * 16 + 8 * h5)];
        sacc[nt] = __builtin_amdgcn_mfma_f32_32x32x16_bf16(kf, qf, sacc[nt], 0, 0, 0);
      }
    }

    // fixed-max softmax + in-register P->bf16 B-fragments + PV
    const u32 mlo = ((u32)mcur) >> (4 * h5);
    const u32 mhi = ((u32)(mcur >> 32)) >> (4 * h5);
    #pragma unroll
    for (int nt = 0; nt < 2; ++nt) {
      const u32 mm = nt ? mhi : mlo;
      float p[16];
      #pragma unroll
      for (int r = 0; r < 16; ++r) {
        const int cb = (r & 3) + 8 * (r >> 2);
        float v = __builtin_exp2f(__builtin_fmaf(sacc[nt][r], SCALE_LOG2E, -16.f));
        v = ((mm >> cb) & 1u) ? v : 0.f;
        l_lane += v;
        p[r] = v;
      }
      #pragma unroll
      for (int ss = 0; ss < 2; ++ss) {
        const int x0 = pk2(p[8 * ss + 0], p[8 * ss + 1]);
        const int x1 = pk2(p[8 * ss + 2], p[8 * ss + 3]);
        const int y0 = pk2(p[8 * ss + 4], p[8 * ss + 5]);
        const int y1 = pk2(p[8 * ss + 6], p[8 * ss + 7]);
        const auto r0 = __builtin_amdgcn_permlane32_swap(x0, y0, false, false);
        const auto r1 = __builtin_amdgcn_permlane32_swap(x1, y1, false, false);
        intx4 wv;
        wv[0] = r0[0]; wv[1] = r1[0]; wv[2] = r0[1]; wv[3] = r1[1];
        const bf16x8 pf = __builtin_bit_cast(bf16x8, wv);
        const int s4 = 2 * nt + ss;
        #pragma unroll
        for (int ot = 0; ot < 2; ++ot) {
          const bf16x8 vf = *(const bf16x8*)&Vts[sw_off(32 * ot + l31, s4 * 16 + 8 * h5)];
          O[ot] = __builtin_amdgcn_mfma_f32_32x32x16_bf16(vf, pf, O[ot], 0, 0, 0);
        }
      }
    }
  }

  // epilogue: denom = own + partner half; transpose O^T -> row-major via Qs (dead)
  const float lsum = l_lane + __shfl_xor(l_lane, 32);
  const float inv = 1.f / lsum;
  __syncthreads();
  #pragma unroll
  for (int ot = 0; ot < 2; ++ot)
    #pragma unroll
    for (int r = 0; r < 16; ++r) {
      const int dv = 32 * ot + (r & 3) + 8 * (r >> 2) + 4 * h5;
      Qs[sw_off(32 * w + l31, dv)] = (__bf16)(O[ot][r] * inv);
    }
  const int erow = 32 * w + (L >> 1);
  const int ecol = (L & 1) * 32;
  bf16_t* dst = &ctx[(size_t)(b * S_LEN + q0 + erow) * DM + h * DK + ecol];
  #pragma unroll
  for (int c8 = 0; c8 < 4; ++c8)
    *(bf16x8*)(dst + 8 * c8) = *(const bf16x8*)&Qs[sw_off(erow, ecol + 8 * c8)];
}

extern "C" void kernel_launch(void* const* d_in, const int* in_sizes, int n_in,
                              void* d_out, int out_size, void* d_ws, size_t ws_size,
                              hipStream_t stream) {
  const float* q  = (const float*)d_in[0];
  const float* k  = (const float*)d_in[1];
  const float* v  = (const float*)d_in[2];
  const int* mask = (const int*)d_in[3];
  const float* Wq = (const float*)d_in[4];
  const float* bq = (const float*)d_in[5];
  const float* Wk = (const float*)d_in[6];
  const float* bk = (const float*)d_in[7];
  const float* Wv = (const float*)d_in[8];
  const float* bv = (const float*)d_in[9];
  const float* Wo = (const float*)d_in[10];
  const float* bo = (const float*)d_in[11];
  float* out = (float*)d_out;

  const size_t SLICE = (size_t)M_ROWS * DM;  // 4M elems
  bf16_t* Xb   = (bf16_t*)d_ws;              // 3 slices (24 MB); reused below
  bf16_t* QKVb = Xb + 3 * SLICE;             // 3 slices (24 MB)
  bf16_t* Wt   = QKVb + 3 * SLICE;           // 4 MM (8 MB)
  u64* mbw     = (u64*)(Wt + (size_t)4 * DM * DM);  // 131072 u64 (1 MB)
  bf16_t* ctx  = Xb;                         // alias slice 0 (Xb dead after gemm_qkv)
  bf16_t* Vtw  = Xb + SLICE;                 // alias slice 1

  pack_mask<<<dim3(512), dim3(256), 0, stream>>>(mask, mbw);
  cvt_inputs<<<dim3(2048, 3), dim3(256), 0, stream>>>(q, k, v, Xb);
  transw_kernel<<<dim3(16, 16, 4), dim3(256), 0, stream>>>(Wq, Wk, Wv, Wo, Wt);
  gemm_qkv<<<dim3(32, 8, 3), dim3(256), 0, stream>>>(Xb, Wt, bq, bk, bv, QKVb);
  transpV<<<dim3(32, 32), dim3(256), 0, stream>>>(QKVb + 2 * SLICE, Vtw);
  attn_kernel<<<dim3(16, 32), dim3(256), 0, stream>>>(QKVb, QKVb + SLICE, Vtw, mbw, ctx);
  gemm_out<<<dim3(32, 8), dim3(256), 0, stream>>>(ctx, Wt + (size_t)3 * DM * DM, bo, out);
}